// Round 4
// baseline (160.981 us; speedup 1.0000x reference)
//
#include <hip/hip_runtime.h>
#include <hip/hip_bf16.h>

// Problem: AdditiveMul  (N_Q=2048, N_K=2048, N_HEAD=8, D_HEAD=64)
// out[i,j,h] = softmax_h( relu( dot(q[i,h,:], attn[0,h,0:64]) + dot(k[j,h,:], attn[0,h,64:128]) ) )
// Output: (2048, 2048, 8) f32 = 134 MB -> store-bandwidth bound (~21 us floor).
//
// R4: one thread per TWO adjacent j. 8 exps per (i,j) (R3 did 16), 64 B
// contiguous loads from sk and 64 B contiguous stores (4x float4) per thread.
// Max-subtraction dropped (relu'd scores are O(1): sigma~0.5, exp<=~20, no
// overflow; absmax headroom 2e-3 vs 1.4e-2 threshold). Divide -> v_rcp_f32.
// NT stores removed (R3 regression vs R1).

#define N_Q   2048
#define N_K   2048
#define N_HEAD 8
#define D_HEAD 64

// ---------------------------------------------------------------------------
// Kernel 1: sq[i,h] = dot(q[i,h,:], attn[h,0:64]); sk[j,h] = dot(k[j,h,:], attn[h,64:128])
// 8 lanes per (row,head); float4 loads; shuffle-reduce. ~16 MB read, a few us.
// ---------------------------------------------------------------------------
__global__ __launch_bounds__(256) void proj_kernel(
    const float* __restrict__ q, const float* __restrict__ k,
    const float* __restrict__ attn,
    float* __restrict__ sq, float* __restrict__ sk)
{
    int tid = blockIdx.x * blockDim.x + threadIdx.x;
    int lane8 = tid & 7;
    int pair  = tid >> 3;                 // [0, 2*N_Q*N_HEAD)
    const int PAIRS = N_Q * N_HEAD;
    bool is_k = pair >= PAIRS;
    int p = is_k ? (pair - PAIRS) : pair; // p = row*8 + h
    int h = p & (N_HEAD - 1);

    const float* src = is_k ? k : q;
    const float* a   = attn + h * (2 * D_HEAD) + (is_k ? D_HEAD : 0);

    const float4* s4 = (const float4*)(src + (size_t)p * D_HEAD + lane8 * 8);
    const float4* a4 = (const float4*)(a + lane8 * 8);
    float4 x0 = s4[0], x1 = s4[1];
    float4 w0 = a4[0], w1 = a4[1];
    float sum = x0.x*w0.x + x0.y*w0.y + x0.z*w0.z + x0.w*w0.w
              + x1.x*w1.x + x1.y*w1.y + x1.z*w1.z + x1.w*w1.w;

    sum += __shfl_xor(sum, 1);
    sum += __shfl_xor(sum, 2);
    sum += __shfl_xor(sum, 4);

    if (lane8 == 0) {
        (is_k ? sk : sq)[p] = sum;
    }
}

// ---------------------------------------------------------------------------
// Kernel 2: one thread per (i, j0..j0+1). Computes two independent 8-head
// softmaxes, writes 64 B contiguous (4x float4). Wave-level: loads and stores
// each cover a dense 4 KB span across 4 instructions.
// ---------------------------------------------------------------------------
__global__ __launch_bounds__(256) void softmax_kernel(
    const float* __restrict__ sq, const float* __restrict__ sk,
    float* __restrict__ out)
{
    int t  = blockIdx.x * blockDim.x + threadIdx.x;  // 0 .. N_K/2-1
    int j0 = t * 2;
    int i  = blockIdx.y;

    // sq[i,:] block-uniform broadcast
    float4 q0 = *(const float4*)(sq + i * N_HEAD);
    float4 q1 = *(const float4*)(sq + i * N_HEAD + 4);
    // sk[j0,:] and sk[j0+1,:] : 64 B contiguous per thread
    const float4* kk = (const float4*)(sk + j0 * N_HEAD);
    float4 a0 = kk[0], a1 = kk[1], b0 = kk[2], b1 = kk[3];

    const float LOG2E = 1.4426950408889634f;

    float va[8], vb[8];
    va[0] = q0.x + a0.x; va[1] = q0.y + a0.y; va[2] = q0.z + a0.z; va[3] = q0.w + a0.w;
    va[4] = q1.x + a1.x; va[5] = q1.y + a1.y; va[6] = q1.z + a1.z; va[7] = q1.w + a1.w;
    vb[0] = q0.x + b0.x; vb[1] = q0.y + b0.y; vb[2] = q0.z + b0.z; vb[3] = q0.w + b0.w;
    vb[4] = q1.x + b1.x; vb[5] = q1.y + b1.y; vb[6] = q1.z + b1.z; vb[7] = q1.w + b1.w;

    float sa = 0.0f, sb = 0.0f;
    #pragma unroll
    for (int h = 0; h < 8; ++h) {
        va[h] = __builtin_amdgcn_exp2f(fmaxf(va[h], 0.0f) * LOG2E);
        sa += va[h];
        vb[h] = __builtin_amdgcn_exp2f(fmaxf(vb[h], 0.0f) * LOG2E);
        sb += vb[h];
    }
    float ra = __builtin_amdgcn_rcpf(sa);
    float rb = __builtin_amdgcn_rcpf(sb);

    float4 o0 = make_float4(va[0]*ra, va[1]*ra, va[2]*ra, va[3]*ra);
    float4 o1 = make_float4(va[4]*ra, va[5]*ra, va[6]*ra, va[7]*ra);
    float4 o2 = make_float4(vb[0]*rb, vb[1]*rb, vb[2]*rb, vb[3]*rb);
    float4 o3 = make_float4(vb[4]*rb, vb[5]*rb, vb[6]*rb, vb[7]*rb);

    float4* dst = (float4*)(out + ((size_t)i * N_K + j0) * N_HEAD);
    dst[0] = o0; dst[1] = o1; dst[2] = o2; dst[3] = o3;
}

extern "C" void kernel_launch(void* const* d_in, const int* in_sizes, int n_in,
                              void* d_out, int out_size, void* d_ws, size_t ws_size,
                              hipStream_t stream) {
    const float* q    = (const float*)d_in[0];
    const float* k    = (const float*)d_in[1];
    const float* attn = (const float*)d_in[2];
    float* out = (float*)d_out;

    float* sq = (float*)d_ws;            // N_Q*N_HEAD floats
    float* sk = sq + N_Q * N_HEAD;       // N_K*N_HEAD floats

    int total_threads = 2 * N_Q * N_HEAD * 8;   // 262144
    proj_kernel<<<dim3(total_threads / 256), dim3(256), 0, stream>>>(q, k, attn, sq, sk);

    // one thread per 2 j's: grid.x = (N_K/2)/256 = 4, grid.y = N_Q
    softmax_kernel<<<dim3(N_K / 2 / 256, N_Q), dim3(256), 0, stream>>>(sq, sk, out);
}

// Round 5
// 139.875 us; speedup vs baseline: 1.1509x; 1.1509x over previous
//
#include <hip/hip_runtime.h>
#include <hip/hip_bf16.h>

// Problem: AdditiveMul  (N_Q=2048, N_K=2048, N_HEAD=8, D_HEAD=64)
// out[i,j,h] = softmax_h( relu( dot(q[i,h,:], attn[0,h,0:64]) + dot(k[j,h,:], attn[0,h,64:128]) ) )
// Output: (2048, 2048, 8) f32 = 134 MB -> store-bandwidth bound.
//
// R5: lane-paired softmax. Lanes 2t/2t+1 handle halves 0/1 of the same j:
//  - each thread loads 16 B of sk (wave load = 1 KB fully dense)
//  - 4 relu+exp2 per thread, denominator completed via __shfl_xor(ps, 1)
//    (8 exps per (i,j) total -- the minimum; R3 did 16)
//  - ONE float4 store per thread at base + t*16: every wave store instruction
//    is 100% dense (1 KB contiguous), non-NT so L2 merges full lines.
// Evidence: R1 (50% dense, non-NT) 144.6us < R3 (dense, NT) 149.4 < R4 (25%
// dense) 161.0 -> density matters, NT hurts. Fill kernel proves 6.7 TB/s
// dense-store ceiling.

#define N_Q   2048
#define N_K   2048
#define N_HEAD 8
#define D_HEAD 64

// ---------------------------------------------------------------------------
// Kernel 1: sq[i,h] = dot(q[i,h,:], attn[h,0:64]); sk[j,h] = dot(k[j,h,:], attn[h,64:128])
// 8 lanes per (row,head); float4 loads; shuffle-reduce. ~34 MB read, ~5 us.
// ---------------------------------------------------------------------------
__global__ __launch_bounds__(256) void proj_kernel(
    const float* __restrict__ q, const float* __restrict__ k,
    const float* __restrict__ attn,
    float* __restrict__ sq, float* __restrict__ sk)
{
    int tid = blockIdx.x * blockDim.x + threadIdx.x;
    int lane8 = tid & 7;
    int pair  = tid >> 3;                 // [0, 2*N_Q*N_HEAD)
    const int PAIRS = N_Q * N_HEAD;
    bool is_k = pair >= PAIRS;
    int p = is_k ? (pair - PAIRS) : pair; // p = row*8 + h
    int h = p & (N_HEAD - 1);

    const float* src = is_k ? k : q;
    const float* a   = attn + h * (2 * D_HEAD) + (is_k ? D_HEAD : 0);

    const float4* s4 = (const float4*)(src + (size_t)p * D_HEAD + lane8 * 8);
    const float4* a4 = (const float4*)(a + lane8 * 8);
    float4 x0 = s4[0], x1 = s4[1];
    float4 w0 = a4[0], w1 = a4[1];
    float sum = x0.x*w0.x + x0.y*w0.y + x0.z*w0.z + x0.w*w0.w
              + x1.x*w1.x + x1.y*w1.y + x1.z*w1.z + x1.w*w1.w;

    sum += __shfl_xor(sum, 1);
    sum += __shfl_xor(sum, 2);
    sum += __shfl_xor(sum, 4);

    if (lane8 == 0) {
        (is_k ? sk : sq)[p] = sum;
    }
}

// ---------------------------------------------------------------------------
// Kernel 2: thread t of row i handles (j = t>>1, half = t&1).
// Loads are dense (sk + t*16 B), store is dense (out_row + t*16 B).
// Denominator shared between the lane pair via shfl_xor(,1).
// ---------------------------------------------------------------------------
__global__ __launch_bounds__(256) void softmax_kernel(
    const float* __restrict__ sq, const float* __restrict__ sk,
    float* __restrict__ out)
{
    int t = blockIdx.x * blockDim.x + threadIdx.x;   // 0 .. 2*N_K-1
    int i = blockIdx.y;

    // this thread's 4 heads: half = t&1
    float4 qv = *(const float4*)(sq + i * N_HEAD + (t & 1) * 4);
    float4 kv = *(const float4*)(sk + t * 4);        // == sk[j*8 + half*4]

    const float LOG2E = 1.4426950408889634f;
    float v0 = __builtin_amdgcn_exp2f(fmaxf(qv.x + kv.x, 0.0f) * LOG2E);
    float v1 = __builtin_amdgcn_exp2f(fmaxf(qv.y + kv.y, 0.0f) * LOG2E);
    float v2 = __builtin_amdgcn_exp2f(fmaxf(qv.z + kv.z, 0.0f) * LOG2E);
    float v3 = __builtin_amdgcn_exp2f(fmaxf(qv.w + kv.w, 0.0f) * LOG2E);

    float ps = (v0 + v1) + (v2 + v3);
    float s  = ps + __shfl_xor(ps, 1);   // partner lane has the other 4 heads
    float r  = __builtin_amdgcn_rcpf(s);

    float4 o = make_float4(v0 * r, v1 * r, v2 * r, v3 * r);
    *(float4*)(out + (size_t)i * N_K * N_HEAD + t * 4) = o;
}

extern "C" void kernel_launch(void* const* d_in, const int* in_sizes, int n_in,
                              void* d_out, int out_size, void* d_ws, size_t ws_size,
                              hipStream_t stream) {
    const float* q    = (const float*)d_in[0];
    const float* k    = (const float*)d_in[1];
    const float* attn = (const float*)d_in[2];
    float* out = (float*)d_out;

    float* sq = (float*)d_ws;            // N_Q*N_HEAD floats
    float* sk = sq + N_Q * N_HEAD;       // N_K*N_HEAD floats

    int total_threads = 2 * N_Q * N_HEAD * 8;   // 262144
    proj_kernel<<<dim3(total_threads / 256), dim3(256), 0, stream>>>(q, k, attn, sq, sk);

    // 2*N_K threads per i-row: grid.x = 4096/256 = 16, grid.y = N_Q
    softmax_kernel<<<dim3(2 * N_K / 256, N_Q), dim3(256), 0, stream>>>(sq, sk, out);
}